// Round 1
// baseline (179.455 us; speedup 1.0000x reference)
//
#include <hip/hip_runtime.h>

// Problem constants (B,N,H,NB,NCT) = (8,4096,1024,128,33), H/2 = 512
#define NTOK 4096
#define HDIM 1024
#define HHALF 512
#define NBLK 128

typedef __attribute__((ext_vector_type(8))) short short8;
typedef __attribute__((ext_vector_type(4))) float f32x4;
typedef short bf16s;

__device__ __forceinline__ short f2bf(float f) {
    unsigned u = __builtin_bit_cast(unsigned, f);
    u = (u + 0x7fffu + ((u >> 16) & 1u)) >> 16;   // RNE round to bf16
    return (short)u;
}

// ---------------------------------------------------------------------------
// Transpose + convert: out[n][k] = (bf16) in[k][n],  K fixed = 1024
// ---------------------------------------------------------------------------
__global__ void k_tcvt(const float* __restrict__ in, bf16s* __restrict__ out, int Nc) {
    size_t g = (size_t)blockIdx.x * 256 + threadIdx.x;
    if (g >= (size_t)Nc * 1024) return;
    int n = (int)(g >> 10);
    int k = (int)(g & 1023);
    out[g] = f2bf(in[(size_t)k * Nc + n]);
}

// ---------------------------------------------------------------------------
// Gate GEMM: gate[row] = sum_c tanh( (x@W1)[row][c] + b1[c] ) * W2[c] + b2
// M=32768 (B*N), N=512 (full width per wg), K=1024. BM=64, BK=32.
// 512 threads = 8 waves laid out 2(row) x 4(col); wave tile 32x128, acc[2][8].
// ---------------------------------------------------------------------------
__global__ void k_gemm_gate(const float* __restrict__ x, const bf16s* __restrict__ w1t,
                            const float* __restrict__ b1, const float* __restrict__ w2,
                            const float* __restrict__ b2, float* __restrict__ gate)
{
    __shared__ alignas(16) bf16s As[64][40];    // stride 40 bf16 = 80B (pad kills conflicts)
    __shared__ alignas(16) bf16s Bs[512][40];
    __shared__ float gp[4][64];

    const int tid = threadIdx.x;
    const int lane = tid & 63;
    const int wv = tid >> 6;
    const int wr = wv >> 2, wc = wv & 3;
    const int row0 = blockIdx.x * 64;
    const int c0 = lane & 15, khalf = lane >> 4;
    const int ar = tid >> 3, ac = tid & 7;      // A staging: 64 rows x 8 chunks(4 f32)

    f32x4 acc[2][8] = {};

    for (int kt = 0; kt < 1024; kt += 32) {
        __syncthreads();
        // stage A tile 64x32: f32 -> bf16
        {
            float4 xv = *reinterpret_cast<const float4*>(
                &x[(size_t)(row0 + ar) * HDIM + kt + ac * 4]);
            short tmp[4] = {f2bf(xv.x), f2bf(xv.y), f2bf(xv.z), f2bf(xv.w)};
            *reinterpret_cast<int2*>(&As[ar][ac * 4]) = *reinterpret_cast<const int2*>(tmp);
        }
        // stage B tile 512x32 from w1t[n][k]
        #pragma unroll
        for (int i = 0; i < 4; ++i) {
            int idx = tid + i * 512;
            int n = idx >> 2, kc = idx & 3;
            *reinterpret_cast<int4*>(&Bs[n][kc * 8]) =
                *reinterpret_cast<const int4*>(&w1t[(size_t)n * 1024 + kt + kc * 8]);
        }
        __syncthreads();

        const int kk = khalf * 8;
        short8 a0 = *reinterpret_cast<const short8*>(&As[wr * 32 + c0][kk]);
        short8 a1 = *reinterpret_cast<const short8*>(&As[wr * 32 + 16 + c0][kk]);
        #pragma unroll
        for (int nf = 0; nf < 8; ++nf) {
            short8 bv = *reinterpret_cast<const short8*>(&Bs[wc * 128 + nf * 16 + c0][kk]);
            acc[0][nf] = __builtin_amdgcn_mfma_f32_16x16x32_bf16(a0, bv, acc[0][nf], 0, 0, 0);
            acc[1][nf] = __builtin_amdgcn_mfma_f32_16x16x32_bf16(a1, bv, acc[1][nf], 0, 0, 0);
        }
    }

    // epilogue: per-row partial = sum over this wave's 128 cols of tanh(h)*W2
    #pragma unroll
    for (int mf = 0; mf < 2; ++mf) {
        #pragma unroll
        for (int reg = 0; reg < 4; ++reg) {
            float s = 0.f;
            #pragma unroll
            for (int nf = 0; nf < 8; ++nf) {
                int gc = wc * 128 + nf * 16 + c0;
                float v = acc[mf][nf][reg] + b1[gc];
                s += tanhf(v) * w2[gc];
            }
            s += __shfl_xor(s, 1); s += __shfl_xor(s, 2);
            s += __shfl_xor(s, 4); s += __shfl_xor(s, 8);
            if (c0 == 0) gp[wc][wr * 32 + mf * 16 + khalf * 4 + reg] = s;
        }
    }
    __syncthreads();
    if (tid < 64)
        gate[row0 + tid] = gp[0][tid] + gp[1][tid] + gp[2][tid] + gp[3][tid] + b2[0];
}

// ---------------------------------------------------------------------------
// Per-(b,block) masked softmax stats: count, max, sum-exp; writes has_b.
// One wave per (b,k).
// ---------------------------------------------------------------------------
__global__ void k_stats(const int* __restrict__ block_ids, const unsigned char* __restrict__ pad,
                        const float* __restrict__ gate, const int* __restrict__ ct,
                        const float* __restrict__ ct_emb,
                        int* __restrict__ counts, float* __restrict__ mblk,
                        float* __restrict__ wscale, float* __restrict__ out_hasb)
{
    const int blk = blockIdx.x;
    const int b = blk >> 7, k = blk & 127;
    const int lane = threadIdx.x;
    const int base = b * NTOK;

    float m = -__builtin_inff();
    int cnt = 0;
    for (int t = lane; t < NTOK; t += 64) {
        bool mt = (block_ids[base + t] == k) && (pad[base + t] == 0);
        if (mt) { m = fmaxf(m, gate[base + t]); cnt++; }
    }
    #pragma unroll
    for (int off = 32; off; off >>= 1) {
        m = fmaxf(m, __shfl_xor(m, off));
        cnt += __shfl_xor(cnt, off);
    }
    float s = 0.f;
    for (int t = lane; t < NTOK; t += 64) {
        bool mt = (block_ids[base + t] == k) && (pad[base + t] == 0);
        if (mt) s += expf(gate[base + t] - m);
    }
    #pragma unroll
    for (int off = 32; off; off >>= 1) s += __shfl_xor(s, off);

    if (lane == 0) {
        counts[blk] = cnt;
        mblk[blk] = m;
        float mod = 1.0f + 0.1f * ct_emb[ct[b] * NBLK + k];
        wscale[blk] = (s > 0.f) ? (mod / fmaxf(s, 1e-30f)) : 0.f;
        out_hasb[blk] = (cnt > 0) ? 1.f : 0.f;
    }
}

// ---------------------------------------------------------------------------
// Exclusive scan of counts per batch (tiny, serial per b — deterministic)
// ---------------------------------------------------------------------------
__global__ void k_offsets(const int* __restrict__ counts, int* __restrict__ offsets) {
    int b = threadIdx.x;
    if (b < 8) {
        int off = 0;
        for (int k = 0; k < NBLK; ++k) {
            offsets[b * NBLK + k] = off;
            off += counts[b * NBLK + k];
        }
    }
}

// ---------------------------------------------------------------------------
// Build ordered member lists (CSR) via ballot+popcount — deterministic order.
// One wave per (b,k).
// ---------------------------------------------------------------------------
__global__ void k_fill(const int* __restrict__ block_ids, const unsigned char* __restrict__ pad,
                       const int* __restrict__ offsets, int* __restrict__ lists)
{
    const int blk = blockIdx.x;
    const int b = blk >> 7, k = blk & 127;
    const int lane = threadIdx.x;
    const int base = b * NTOK;
    int pos = offsets[blk];
    for (int t0 = 0; t0 < NTOK; t0 += 64) {
        int t = t0 + lane;
        bool mt = (block_ids[base + t] == k) && (pad[base + t] == 0);
        unsigned long long mask = __ballot(mt);
        if (mt) {
            int my = __popcll(mask & ((1ull << lane) - 1ull));
            lists[base + pos + my] = t;
        }
        pos += __popcll(mask);
    }
}

// ---------------------------------------------------------------------------
// Pooling: pooled[b,k,:] = sum_{n in block} w_n * x[b,n,:], w_n = exp(g-m)*wscale
// One wg (256 thr) per (b,k); thread owns 4 consecutive h. x read exactly once.
// ---------------------------------------------------------------------------
__global__ void k_pool(const float* __restrict__ x, const float* __restrict__ gate,
                       const int* __restrict__ lists, const int* __restrict__ counts,
                       const int* __restrict__ offsets, const float* __restrict__ mblk,
                       const float* __restrict__ wscale, bf16s* __restrict__ pooled)
{
    const int blk = blockIdx.x;
    const int b = blk >> 7;
    const int tid = threadIdx.x;
    const int base = b * NTOK;
    const int cnt = counts[blk];
    const int off = offsets[blk];
    const float m = mblk[blk], ws = wscale[blk];

    float4 acc = {0.f, 0.f, 0.f, 0.f};
    for (int i = 0; i < cnt; ++i) {
        int n = lists[base + off + i];
        float w = expf(gate[base + n] - m) * ws;
        float4 xv = *reinterpret_cast<const float4*>(&x[(size_t)(base + n) * HDIM + tid * 4]);
        acc.x += w * xv.x; acc.y += w * xv.y; acc.z += w * xv.z; acc.w += w * xv.w;
    }
    short o[4] = {f2bf(acc.x), f2bf(acc.y), f2bf(acc.z), f2bf(acc.w)};
    *reinterpret_cast<int2*>(&pooled[(size_t)blk * HDIM + tid * 4]) =
        *reinterpret_cast<const int2*>(o);
}

// ---------------------------------------------------------------------------
// GEMM2: y = pooled @ Wp + bp.  M=N=K=1024. 64x64 tiles, 4 waves (2x2), BK=32.
// ---------------------------------------------------------------------------
__global__ void k_gemm2(const bf16s* __restrict__ pooled, const bf16s* __restrict__ wpt,
                        const float* __restrict__ bp, float* __restrict__ y)
{
    __shared__ alignas(16) bf16s As[64][40];
    __shared__ alignas(16) bf16s Bs[64][40];
    const int tid = threadIdx.x;
    const int lane = tid & 63;
    const int wv = tid >> 6;
    const int wr = wv >> 1, wc = wv & 1;
    const int row0 = (blockIdx.x >> 4) * 64, col0 = (blockIdx.x & 15) * 64;
    const int c0 = lane & 15, khalf = lane >> 4;
    const int sr = tid >> 2, sc = tid & 3;

    f32x4 acc[2][2] = {};
    for (int kt = 0; kt < 1024; kt += 32) {
        __syncthreads();
        *reinterpret_cast<int4*>(&As[sr][sc * 8]) =
            *reinterpret_cast<const int4*>(&pooled[(size_t)(row0 + sr) * 1024 + kt + sc * 8]);
        *reinterpret_cast<int4*>(&Bs[sr][sc * 8]) =
            *reinterpret_cast<const int4*>(&wpt[(size_t)(col0 + sr) * 1024 + kt + sc * 8]);
        __syncthreads();
        const int kk = khalf * 8;
        #pragma unroll
        for (int mf = 0; mf < 2; ++mf) {
            short8 av = *reinterpret_cast<const short8*>(&As[wr * 32 + mf * 16 + c0][kk]);
            #pragma unroll
            for (int nf = 0; nf < 2; ++nf) {
                short8 bv = *reinterpret_cast<const short8*>(&Bs[wc * 32 + nf * 16 + c0][kk]);
                acc[mf][nf] = __builtin_amdgcn_mfma_f32_16x16x32_bf16(av, bv, acc[mf][nf], 0, 0, 0);
            }
        }
    }
    #pragma unroll
    for (int mf = 0; mf < 2; ++mf)
        #pragma unroll
        for (int nf = 0; nf < 2; ++nf)
            #pragma unroll
            for (int reg = 0; reg < 4; ++reg) {
                int grow = row0 + wr * 32 + mf * 16 + khalf * 4 + reg;
                int gcol = col0 + wc * 32 + nf * 16 + c0;
                y[(size_t)grow * 1024 + gcol] = acc[mf][nf][reg] + bp[gcol];
            }
}

// ---------------------------------------------------------------------------
// LayerNorm + ELU + present-mask; writes block_tokens. One wg per (b,k) row.
// ---------------------------------------------------------------------------
__global__ void k_lnelu(const float* __restrict__ y, const float* __restrict__ ln_g,
                        const float* __restrict__ ln_b, const int* __restrict__ counts,
                        float* __restrict__ outp)
{
    const int row = blockIdx.x;
    const int k = row & 127;
    const int tid = threadIdx.x;

    float4 v = *reinterpret_cast<const float4*>(&y[(size_t)row * 1024 + tid * 4]);
    float s = v.x + v.y + v.z + v.w;
    float ss = v.x * v.x + v.y * v.y + v.z * v.z + v.w * v.w;
    #pragma unroll
    for (int off = 32; off; off >>= 1) { s += __shfl_xor(s, off); ss += __shfl_xor(ss, off); }

    __shared__ float sbuf[4], ssbuf[4];
    int wv = tid >> 6;
    if ((tid & 63) == 0) { sbuf[wv] = s; ssbuf[wv] = ss; }
    __syncthreads();
    s = sbuf[0] + sbuf[1] + sbuf[2] + sbuf[3];
    ss = ssbuf[0] + ssbuf[1] + ssbuf[2] + ssbuf[3];

    float mu = s * (1.f / 1024.f);
    float var = ss * (1.f / 1024.f) - mu * mu;
    float rstd = rsqrtf(var + 1e-5f);

    bool pres = false;
    #pragma unroll
    for (int bb = 0; bb < 8; ++bb) pres = pres || (counts[bb * NBLK + k] > 0);

    float4 g4 = *reinterpret_cast<const float4*>(&ln_g[tid * 4]);
    float4 b4 = *reinterpret_cast<const float4*>(&ln_b[tid * 4]);
    float vals[4] = {v.x, v.y, v.z, v.w};
    float gs[4] = {g4.x, g4.y, g4.z, g4.w};
    float bs[4] = {b4.x, b4.y, b4.z, b4.w};
    float4 o;
    float* op = &o.x;
    #pragma unroll
    for (int j = 0; j < 4; ++j) {
        float t = (vals[j] - mu) * rstd * gs[j] + bs[j];
        t = (t > 0.f) ? t : expm1f(t);
        op[j] = pres ? t : 0.f;
    }
    *reinterpret_cast<float4*>(&outp[(size_t)row * 1024 + tid * 4]) = o;
}

// ---------------------------------------------------------------------------
extern "C" void kernel_launch(void* const* d_in, const int* in_sizes, int n_in,
                              void* d_out, int out_size, void* d_ws, size_t ws_size,
                              hipStream_t stream)
{
    const float* x      = (const float*)d_in[0];
    const int*   ct     = (const int*)d_in[1];
    const int*   bids   = (const int*)d_in[2];
    const unsigned char* pad = (const unsigned char*)d_in[3];
    const float* W1     = (const float*)d_in[4];
    const float* b1     = (const float*)d_in[5];
    const float* W2     = (const float*)d_in[6];
    const float* b2     = (const float*)d_in[7];
    const float* ct_emb = (const float*)d_in[8];
    const float* Wp     = (const float*)d_in[9];
    const float* bp     = (const float*)d_in[10];
    const float* ln_g   = (const float*)d_in[11];
    const float* ln_b   = (const float*)d_in[12];
    float* outF = (float*)d_out;

    char* ws = (char*)d_ws;
    bf16s* w1t    = (bf16s*)(ws + 0);          //   512*1024*2 = 1,048,576
    bf16s* wpt    = (bf16s*)(ws + 1048576);    //  1024*1024*2 = 2,097,152
    float* gate   = (float*)(ws + 3145728);    //  32768*4     =   131,072
    float* mblk   = (float*)(ws + 3276800);    //   1024*4
    float* wscal  = (float*)(ws + 3280896);    //   1024*4
    int*   counts = (int*)  (ws + 3284992);    //   1024*4
    int*   offs   = (int*)  (ws + 3289088);    //   1024*4
    int*   lists  = (int*)  (ws + 3293184);    //  32768*4     =   131,072
    bf16s* pooled = (bf16s*)(ws + 3424256);    //  1024*1024*2 = 2,097,152
    float* ybuf   = (float*)(ws + 5521408);    //  1024*1024*4 = 4,194,304
    // total ~9.7 MB

    k_tcvt<<<2048, 256, 0, stream>>>(W1, w1t, HHALF);
    k_tcvt<<<4096, 256, 0, stream>>>(Wp, wpt, HDIM);
    k_gemm_gate<<<512, 512, 0, stream>>>(x, w1t, b1, W2, b2, gate);
    k_stats<<<1024, 64, 0, stream>>>(bids, pad, gate, ct, ct_emb, counts, mblk, wscal,
                                     outF + (size_t)8 * NBLK * HDIM);
    k_offsets<<<1, 8, 0, stream>>>(counts, offs);
    k_fill<<<1024, 64, 0, stream>>>(bids, pad, offs, lists);
    k_pool<<<1024, 256, 0, stream>>>(x, gate, lists, counts, offs, mblk, wscal, pooled);
    k_gemm2<<<256, 256, 0, stream>>>(pooled, wpt, bp, ybuf);
    k_lnelu<<<1024, 256, 0, stream>>>(ybuf, ln_g, ln_b, counts, outF);
}